// Round 1
// baseline (739.997 us; speedup 1.0000x reference)
//
#include <hip/hip_runtime.h>
#include <math.h>

#define D      128
#define TM     64      // points per block tile
#define TK     64      // codes per chunk
#define LDROW  33      // float4 row stride in LDS (32 data + 1 pad) -> conflict-free b128 reads
#define INV_T  (1.0f / 0.9f)

// ---------------------------------------------------------------------------
// Kernel 0: e_sq[c] = sum_d embed[c][d]^2 ; also zero the class accumulator.
// One wave (64 threads) per code.
// ---------------------------------------------------------------------------
__global__ void prep_kernel(const float* __restrict__ embed,
                            float* __restrict__ e_sq,
                            float* __restrict__ classacc) {
    const int c = blockIdx.x;
    const int t = threadIdx.x;  // 0..63
    float v0 = embed[(size_t)c * D + t];
    float v1 = embed[(size_t)c * D + 64 + t];
    float s = v0 * v0 + v1 * v1;
    #pragma unroll
    for (int off = 32; off > 0; off >>= 1) s += __shfl_down(s, off, 64);
    if (t == 0) {
        e_sq[c] = s;
        classacc[c] = 0.0f;   // zeroed for pass2 atomics (ws is poisoned 0xAA)
    }
}

// ---------------------------------------------------------------------------
// Pass 1: for each point, over all K codes: s = 2*dot(x,e) - e_sq.
// Online: running max m, argmax (first-index tie-break), rescaled exp-sum l.
// Writes: quantize gather -> q_out, embed_ind (as float) -> ind_out,
//         m[N] and r[N]=1/l to workspace for pass 2.
// Block: 256 threads = 16 tx (codes) x 16 ty (points); strided 4x4 micro-tile:
//   thread covers points {ty+16i} and codes {tx+16j} -> conflict-free LDS b128.
// ---------------------------------------------------------------------------
__global__ __launch_bounds__(256)
void pass1_kernel(const float* __restrict__ x, const float* __restrict__ embed,
                  const float* __restrict__ e_sq_g, float* __restrict__ m_out,
                  float* __restrict__ r_out, float* __restrict__ q_out,
                  float* __restrict__ ind_out, int K) {
    __shared__ float4 xsf4[TM * LDROW];   // 33 KB, layout [row][d4], stride 33
    __shared__ float4 esf4[TK * LDROW];   // 33 KB

    const int tid = threadIdx.x;
    const int tx = tid & 15;
    const int ty = tid >> 4;
    const int p0 = blockIdx.x * TM;

    // stage x tile (rows p0..p0+63), coalesced float4 loads
    #pragma unroll
    for (int it = 0; it < 8; ++it) {
        int j = tid + it * 256;          // 2048 float4
        int r = j >> 5;                  // 0..63
        int d4 = j & 31;                 // 0..31
        xsf4[r * LDROW + d4] =
            reinterpret_cast<const float4*>(x)[(size_t)(p0 + r) * 32 + d4];
    }

    float m_run[4], l_run[4];
    int   i_run[4];
    #pragma unroll
    for (int i = 0; i < 4; ++i) { m_run[i] = -INFINITY; l_run[i] = 0.0f; i_run[i] = 0; }

    const int nch = K / TK;
    for (int ch = 0; ch < nch; ++ch) {
        __syncthreads();
        #pragma unroll
        for (int it = 0; it < 8; ++it) {
            int j = tid + it * 256;
            int r = j >> 5;
            int d4 = j & 31;
            esf4[r * LDROW + d4] =
                reinterpret_cast<const float4*>(embed)[(size_t)(ch * TK + r) * 32 + d4];
        }
        __syncthreads();

        float acc[4][4];
        #pragma unroll
        for (int i = 0; i < 4; ++i)
            #pragma unroll
            for (int jj = 0; jj < 4; ++jj) acc[i][jj] = 0.0f;

        #pragma unroll 4
        for (int d4 = 0; d4 < 32; ++d4) {
            float4 a0 = xsf4[(ty     ) * LDROW + d4];
            float4 a1 = xsf4[(ty + 16) * LDROW + d4];
            float4 a2 = xsf4[(ty + 32) * LDROW + d4];
            float4 a3 = xsf4[(ty + 48) * LDROW + d4];
            float4 b0 = esf4[(tx     ) * LDROW + d4];
            float4 b1 = esf4[(tx + 16) * LDROW + d4];
            float4 b2 = esf4[(tx + 32) * LDROW + d4];
            float4 b3 = esf4[(tx + 48) * LDROW + d4];
            float4 av[4] = {a0, a1, a2, a3};
            float4 bv[4] = {b0, b1, b2, b3};
            #pragma unroll
            for (int i = 0; i < 4; ++i)
                #pragma unroll
                for (int jj = 0; jj < 4; ++jj) {
                    acc[i][jj] += av[i].x * bv[jj].x;
                    acc[i][jj] += av[i].y * bv[jj].y;
                    acc[i][jj] += av[i].z * bv[jj].z;
                    acc[i][jj] += av[i].w * bv[jj].w;
                }
        }

        float esq[4];
        #pragma unroll
        for (int jj = 0; jj < 4; ++jj) esq[jj] = e_sq_g[ch * TK + tx + 16 * jj];

        #pragma unroll
        for (int i = 0; i < 4; ++i) {
            float s[4];
            #pragma unroll
            for (int jj = 0; jj < 4; ++jj) s[jj] = 2.0f * acc[i][jj] - esq[jj];
            // local best (codes ascending in jj -> strict > keeps first index)
            float lm = s[0]; int li = ch * TK + tx;
            #pragma unroll
            for (int jj = 1; jj < 4; ++jj) {
                int c = ch * TK + tx + 16 * jj;
                if (s[jj] > lm) { lm = s[jj]; li = c; }
            }
            float om = m_run[i];
            float nm = fmaxf(om, lm);
            if (lm > om || (lm == om && li < i_run[i])) i_run[i] = li;
            float l = l_run[i] * __expf((om - nm) * INV_T);
            #pragma unroll
            for (int jj = 0; jj < 4; ++jj) l += __expf((s[jj] - nm) * INV_T);
            m_run[i] = nm;
            l_run[i] = l;
        }
    }

    // cross-thread (tx) reduction per point row; alias reduction scratch on esf4
    __syncthreads();
    float* mred = reinterpret_cast<float*>(esf4);
    float* lred = mred + TM * 16;
    int*   ired = reinterpret_cast<int*>(lred + TM * 16);
    int*   idxs = ired + TM * 16;
    #pragma unroll
    for (int i = 0; i < 4; ++i) {
        int row = ty + 16 * i;
        mred[row * 16 + tx] = m_run[i];
        lred[row * 16 + tx] = l_run[i];
        ired[row * 16 + tx] = i_run[i];
    }
    __syncthreads();
    if (tid < TM) {
        int row = tid;
        float bm = mred[row * 16]; int bi = ired[row * 16];
        for (int t = 1; t < 16; ++t) {
            float v = mred[row * 16 + t]; int c = ired[row * 16 + t];
            if (v > bm || (v == bm && c < bi)) { bm = v; bi = c; }
        }
        float l = 0.0f;
        for (int t = 0; t < 16; ++t)
            l += lred[row * 16 + t] * __expf((mred[row * 16 + t] - bm) * INV_T);
        int gp = p0 + row;
        m_out[gp] = bm;
        r_out[gp] = 1.0f / l;
        ind_out[gp] = (float)bi;
        idxs[row] = bi;
    }
    __syncthreads();
    // gather quantize rows (exact copies of embed rows)
    #pragma unroll
    for (int it = 0; it < 8; ++it) {
        int j = tid + it * 256;
        int r = j >> 5;
        int d4 = j & 31;
        reinterpret_cast<float4*>(q_out)[(size_t)(p0 + r) * 32 + d4] =
            reinterpret_cast<const float4*>(embed)[(size_t)idxs[r] * 32 + d4];
    }
}

// ---------------------------------------------------------------------------
// Pass 2: recompute s, accumulate class_sums[k] += exp((s - m_p)/T) * r_p
// into LDS histogram, flush once per block via global atomics.
// ---------------------------------------------------------------------------
__global__ __launch_bounds__(256)
void pass2_kernel(const float* __restrict__ x, const float* __restrict__ embed,
                  const float* __restrict__ e_sq_g, const float* __restrict__ m_in,
                  const float* __restrict__ r_in, float* __restrict__ classacc, int K) {
    __shared__ float4 xsf4[TM * LDROW];
    __shared__ float4 esf4[TK * LDROW];
    __shared__ float  cacc[2048];

    const int tid = threadIdx.x;
    const int tx = tid & 15;
    const int ty = tid >> 4;
    const int p0 = blockIdx.x * TM;

    for (int i = tid; i < K; i += 256) cacc[i] = 0.0f;

    #pragma unroll
    for (int it = 0; it < 8; ++it) {
        int j = tid + it * 256;
        int r = j >> 5;
        int d4 = j & 31;
        xsf4[r * LDROW + d4] =
            reinterpret_cast<const float4*>(x)[(size_t)(p0 + r) * 32 + d4];
    }

    float mrow[4], rrow[4];
    #pragma unroll
    for (int i = 0; i < 4; ++i) {
        mrow[i] = m_in[p0 + ty + 16 * i];
        rrow[i] = r_in[p0 + ty + 16 * i];
    }

    const int nch = K / TK;
    for (int ch = 0; ch < nch; ++ch) {
        __syncthreads();
        #pragma unroll
        for (int it = 0; it < 8; ++it) {
            int j = tid + it * 256;
            int r = j >> 5;
            int d4 = j & 31;
            esf4[r * LDROW + d4] =
                reinterpret_cast<const float4*>(embed)[(size_t)(ch * TK + r) * 32 + d4];
        }
        __syncthreads();

        float acc[4][4];
        #pragma unroll
        for (int i = 0; i < 4; ++i)
            #pragma unroll
            for (int jj = 0; jj < 4; ++jj) acc[i][jj] = 0.0f;

        #pragma unroll 4
        for (int d4 = 0; d4 < 32; ++d4) {
            float4 a0 = xsf4[(ty     ) * LDROW + d4];
            float4 a1 = xsf4[(ty + 16) * LDROW + d4];
            float4 a2 = xsf4[(ty + 32) * LDROW + d4];
            float4 a3 = xsf4[(ty + 48) * LDROW + d4];
            float4 b0 = esf4[(tx     ) * LDROW + d4];
            float4 b1 = esf4[(tx + 16) * LDROW + d4];
            float4 b2 = esf4[(tx + 32) * LDROW + d4];
            float4 b3 = esf4[(tx + 48) * LDROW + d4];
            float4 av[4] = {a0, a1, a2, a3};
            float4 bv[4] = {b0, b1, b2, b3};
            #pragma unroll
            for (int i = 0; i < 4; ++i)
                #pragma unroll
                for (int jj = 0; jj < 4; ++jj) {
                    acc[i][jj] += av[i].x * bv[jj].x;
                    acc[i][jj] += av[i].y * bv[jj].y;
                    acc[i][jj] += av[i].z * bv[jj].z;
                    acc[i][jj] += av[i].w * bv[jj].w;
                }
        }

        float esq[4];
        #pragma unroll
        for (int jj = 0; jj < 4; ++jj) esq[jj] = e_sq_g[ch * TK + tx + 16 * jj];

        #pragma unroll
        for (int jj = 0; jj < 4; ++jj) {
            float wsum = 0.0f;
            #pragma unroll
            for (int i = 0; i < 4; ++i) {
                float s = 2.0f * acc[i][jj] - esq[jj];
                wsum += __expf((s - mrow[i]) * INV_T) * rrow[i];
            }
            atomicAdd(&cacc[ch * TK + tx + 16 * jj], wsum);
        }
    }

    __syncthreads();
    for (int i = tid; i < K; i += 256) atomicAdd(&classacc[i], cacc[i]);
}

// ---------------------------------------------------------------------------
// Finalize: loss = sum_k cp_k * log(cp_k + eps), cp = classacc / N
// ---------------------------------------------------------------------------
__global__ void finalize_kernel(const float* __restrict__ classacc,
                                float* __restrict__ loss_out, int N, int K) {
    __shared__ float red[256];
    const int tid = threadIdx.x;
    float s = 0.0f;
    const float invN = 1.0f / (float)N;
    for (int i = tid; i < K; i += 256) {
        float cp = classacc[i] * invN;
        s += cp * logf(cp + 1e-6f);
    }
    red[tid] = s;
    __syncthreads();
    for (int off = 128; off > 0; off >>= 1) {
        if (tid < off) red[tid] += red[tid + off];
        __syncthreads();
    }
    if (tid == 0) loss_out[0] = red[0];
}

extern "C" void kernel_launch(void* const* d_in, const int* in_sizes, int n_in,
                              void* d_out, int out_size, void* d_ws, size_t ws_size,
                              hipStream_t stream) {
    const float* x     = (const float*)d_in[0];
    const float* embed = (const float*)d_in[1];
    const int N = in_sizes[0] / D;   // 32768
    const int K = in_sizes[1] / D;   // 2048

    float* out      = (float*)d_out;
    float* q_out    = out;                       // N*D floats
    float* ind_out  = out + (size_t)N * D;       // N floats (indices as float)
    float* loss_out = ind_out + N;               // 1 float

    float* e_sq  = (float*)d_ws;                 // K
    float* m_buf = e_sq + K;                     // N
    float* r_buf = m_buf + N;                    // N
    float* cacc  = r_buf + N;                    // K

    prep_kernel<<<K, 64, 0, stream>>>(embed, e_sq, cacc);
    pass1_kernel<<<N / TM, 256, 0, stream>>>(x, embed, e_sq, m_buf, r_buf,
                                             q_out, ind_out, K);
    pass2_kernel<<<N / TM, 256, 0, stream>>>(x, embed, e_sq, m_buf, r_buf,
                                             cacc, K);
    finalize_kernel<<<1, 256, 0, stream>>>(cacc, loss_out, N, K);
}

// Round 2
// 225.651 us; speedup vs baseline: 3.2794x; 3.2794x over previous
//
#include <hip/hip_runtime.h>
#include <math.h>

#define D        128
#define TM       64          // points per block
#define TKC      64          // codes per chunk
#define ESTRIDE  136         // halves per LDS row (128 + 8 pad) -> 2-way max on ds_read_b128
#define INV_T    (1.0f / 0.9f)
#define LO_SCALE 4096.0f
#define LO_INV   (1.0f / 4096.0f)

typedef _Float16 half8 __attribute__((ext_vector_type(8)));
typedef float    f32x4 __attribute__((ext_vector_type(4)));

// ---------------------------------------------------------------------------
// Prep: e_sq[c], fp16 hi/lo split of embed (lo pre-scaled by 4096), zero the
// global class accumulator. One wave per code.
// ---------------------------------------------------------------------------
__global__ void prep_kernel(const float* __restrict__ embed,
                            float* __restrict__ e_sq,
                            _Float16* __restrict__ e_hi,
                            _Float16* __restrict__ e_lo,
                            float* __restrict__ classacc) {
    const int c = blockIdx.x;
    const int t = threadIdx.x;  // 0..63
    float v0 = embed[(size_t)c * D + t];
    float v1 = embed[(size_t)c * D + 64 + t];
    _Float16 h0 = (_Float16)v0;
    _Float16 h1 = (_Float16)v1;
    e_hi[(size_t)c * D + t]      = h0;
    e_hi[(size_t)c * D + 64 + t] = h1;
    e_lo[(size_t)c * D + t]      = (_Float16)((v0 - (float)h0) * LO_SCALE);
    e_lo[(size_t)c * D + 64 + t] = (_Float16)((v1 - (float)h1) * LO_SCALE);
    float s = v0 * v0 + v1 * v1;
    #pragma unroll
    for (int off = 32; off > 0; off >>= 1) s += __shfl_down(s, off, 64);
    if (t == 0) {
        e_sq[c] = s;
        classacc[c] = 0.0f;
    }
}

// stage one 64-code chunk of e_hi/e_lo into padded LDS (uint4 = 8 halves)
__device__ __forceinline__ void stage_e(const uint4* __restrict__ ehi_g4,
                                        const uint4* __restrict__ elo_g4,
                                        _Float16* ehi, _Float16* elo,
                                        int ch, int tid) {
    #pragma unroll
    for (int it = 0; it < 4; ++it) {
        int j   = tid + it * 256;      // 0..1023 uint4 within chunk
        int row = j >> 4;              // 0..63 code row
        int c8  = j & 15;              // 8-half group
        uint4 vh = ehi_g4[(size_t)ch * (TKC * 16) + j];
        uint4 vl = elo_g4[(size_t)ch * (TKC * 16) + j];
        *(uint4*)&ehi[row * ESTRIDE + c8 * 8] = vh;
        *(uint4*)&elo[row * ESTRIDE + c8 * 8] = vl;
    }
}

// one chunk of MFMAs: 4 k-steps x 4 code-tiles x 3 split terms
__device__ __forceinline__ void mfma_chunk(const _Float16* ehi, const _Float16* elo,
                                           const half8* ahi, const half8* alo,
                                           int col, int quad,
                                           f32x4 chh[4], f32x4 cx[4]) {
    #pragma unroll
    for (int kk = 0; kk < 4; ++kk) {
        #pragma unroll
        for (int t = 0; t < 4; ++t) {
            const int boff = (16 * t + col) * ESTRIDE + kk * 32 + quad * 8;
            half8 bhi = *(const half8*)&ehi[boff];
            half8 blo = *(const half8*)&elo[boff];
            chh[t] = __builtin_amdgcn_mfma_f32_16x16x32_f16(ahi[kk], bhi, chh[t], 0, 0, 0);
            cx[t]  = __builtin_amdgcn_mfma_f32_16x16x32_f16(ahi[kk], blo, cx[t], 0, 0, 0);
            cx[t]  = __builtin_amdgcn_mfma_f32_16x16x32_f16(alo[kk], bhi, cx[t], 0, 0, 0);
        }
    }
}

// ---------------------------------------------------------------------------
// Fused: sweep A (l = sum exp(s/T), argmax) + sweep B (class accumulation).
// Block: 256 threads = 4 waves x 16 points = 64 points, loop over 32 chunks.
// MFMA 16x16x32 f16: A[m=lane&15][k=quad*8+j], B[n=lane&15][k=quad*8+j],
// C/D: col=lane&15, row=quad*4+reg.
// ---------------------------------------------------------------------------
__global__ __launch_bounds__(256)
void fused_kernel(const float* __restrict__ x, const float* __restrict__ embed,
                  const _Float16* __restrict__ e_hi_g, const _Float16* __restrict__ e_lo_g,
                  const float* __restrict__ e_sq_g,
                  float* __restrict__ classacc,
                  float* __restrict__ q_out, float* __restrict__ ind_out, int K) {
    __shared__ _Float16 ehi[TKC * ESTRIDE];   // 17.4 KB
    __shared__ _Float16 elo[TKC * ESTRIDE];   // 17.4 KB
    __shared__ float esq_s[2048];             // 8 KB
    __shared__ float cacc_s[2048];            // 8 KB
    __shared__ float r_s[TM];
    __shared__ int   idx_s[TM];

    const int tid  = threadIdx.x;
    const int w    = tid >> 6;
    const int lane = tid & 63;
    const int col  = lane & 15;
    const int quad = lane >> 4;
    const int p0   = blockIdx.x * TM;
    const int pr   = p0 + 16 * w + col;   // this lane's point row

    for (int i = tid; i < K; i += 256) { esq_s[i] = e_sq_g[i]; cacc_s[i] = 0.0f; }

    // A fragments straight from global, split hi/lo (lo scaled by 4096)
    half8 ahi[4], alo[4];
    #pragma unroll
    for (int kk = 0; kk < 4; ++kk) {
        const float* src = x + (size_t)pr * D + kk * 32 + quad * 8;
        #pragma unroll
        for (int j = 0; j < 8; ++j) {
            float v = src[j];
            _Float16 h = (_Float16)v;
            ahi[kk][j] = h;
            alo[kk][j] = (_Float16)((v - (float)h) * LO_SCALE);
        }
    }

    const uint4* ehi_g4 = (const uint4*)e_hi_g;
    const uint4* elo_g4 = (const uint4*)e_lo_g;
    const int nch = K / TKC;

    // ---- sweep A: l (no max-shift; values are tiny but normal fp32) + argmax
    float lrun[4] = {0.f, 0.f, 0.f, 0.f};
    float bval[4] = {-INFINITY, -INFINITY, -INFINITY, -INFINITY};
    int   bidx[4] = {0, 0, 0, 0};

    for (int ch = 0; ch < nch; ++ch) {
        __syncthreads();
        stage_e(ehi_g4, elo_g4, ehi, elo, ch, tid);
        __syncthreads();
        f32x4 chh[4], cx[4];
        #pragma unroll
        for (int t = 0; t < 4; ++t) { chh[t] = (f32x4){0,0,0,0}; cx[t] = (f32x4){0,0,0,0}; }
        mfma_chunk(ehi, elo, ahi, alo, col, quad, chh, cx);
        #pragma unroll
        for (int t = 0; t < 4; ++t) {
            const int code = ch * TKC + 16 * t + col;
            const float esq = esq_s[code];
            #pragma unroll
            for (int r = 0; r < 4; ++r) {
                float s = 2.0f * (chh[t][r] + cx[t][r] * LO_INV) - esq;
                lrun[r] += __expf(s * INV_T);
                if (s > bval[r]) { bval[r] = s; bidx[r] = code; }  // codes ascend -> first-index ties
            }
        }
    }

    // reduce across the 16 lanes of each quad-group (cols of the row)
    #pragma unroll
    for (int r = 0; r < 4; ++r) {
        float v = bval[r]; int bi = bidx[r]; float l = lrun[r];
        #pragma unroll
        for (int off = 8; off >= 1; off >>= 1) {
            float ov = __shfl_xor(v, off, 16);
            int   oi = __shfl_xor(bi, off, 16);
            float ol = __shfl_xor(l, off, 16);
            l += ol;
            if (ov > v || (ov == v && oi < bi)) { v = ov; bi = oi; }
        }
        if (col == 0) {
            int row = 16 * w + quad * 4 + r;
            r_s[row]   = 1.0f / l;
            idx_s[row] = bi;
            ind_out[p0 + row] = (float)bi;
        }
    }
    __syncthreads();

    float rrow[4];
    #pragma unroll
    for (int r = 0; r < 4; ++r) rrow[r] = r_s[16 * w + quad * 4 + r];

    // ---- sweep B: class accumulation p = exp(s/T) * r
    for (int ch = 0; ch < nch; ++ch) {
        __syncthreads();
        stage_e(ehi_g4, elo_g4, ehi, elo, ch, tid);
        __syncthreads();
        f32x4 chh[4], cx[4];
        #pragma unroll
        for (int t = 0; t < 4; ++t) { chh[t] = (f32x4){0,0,0,0}; cx[t] = (f32x4){0,0,0,0}; }
        mfma_chunk(ehi, elo, ahi, alo, col, quad, chh, cx);
        #pragma unroll
        for (int t = 0; t < 4; ++t) {
            const int code = ch * TKC + 16 * t + col;
            const float esq = esq_s[code];
            float wsum = 0.0f;
            #pragma unroll
            for (int r = 0; r < 4; ++r) {
                float s = 2.0f * (chh[t][r] + cx[t][r] * LO_INV) - esq;
                wsum += __expf(s * INV_T) * rrow[r];
            }
            wsum += __shfl_xor(wsum, 16, 64);   // sum the 4 quads' rows
            wsum += __shfl_xor(wsum, 32, 64);
            if (quad == 0) atomicAdd(&cacc_s[code], wsum);
        }
    }

    __syncthreads();
    for (int i = tid; i < K; i += 256) atomicAdd(&classacc[i], cacc_s[i]);

    // quantize gather
    const float4* emb4 = (const float4*)embed;
    float4* q4 = (float4*)q_out;
    #pragma unroll
    for (int it = 0; it < 8; ++it) {
        int j = tid + it * 256;
        int row = j >> 5, d4 = j & 31;
        q4[(size_t)(p0 + row) * 32 + d4] = emb4[(size_t)idx_s[row] * 32 + d4];
    }
}

// ---------------------------------------------------------------------------
__global__ void finalize_kernel(const float* __restrict__ classacc,
                                float* __restrict__ loss_out, int N, int K) {
    __shared__ float red[256];
    const int tid = threadIdx.x;
    float s = 0.0f;
    const float invN = 1.0f / (float)N;
    for (int i = tid; i < K; i += 256) {
        float cp = classacc[i] * invN;
        s += cp * logf(cp + 1e-6f);
    }
    red[tid] = s;
    __syncthreads();
    for (int off = 128; off > 0; off >>= 1) {
        if (tid < off) red[tid] += red[tid + off];
        __syncthreads();
    }
    if (tid == 0) loss_out[0] = red[0];
}

extern "C" void kernel_launch(void* const* d_in, const int* in_sizes, int n_in,
                              void* d_out, int out_size, void* d_ws, size_t ws_size,
                              hipStream_t stream) {
    const float* x     = (const float*)d_in[0];
    const float* embed = (const float*)d_in[1];
    const int N = in_sizes[0] / D;   // 32768
    const int K = in_sizes[1] / D;   // 2048

    float* out      = (float*)d_out;
    float* q_out    = out;
    float* ind_out  = out + (size_t)N * D;
    float* loss_out = ind_out + N;

    float*    e_sq = (float*)d_ws;                    // K
    float*    cacc = e_sq + K;                        // K
    _Float16* e_hi = (_Float16*)(cacc + K);           // K*D
    _Float16* e_lo = e_hi + (size_t)K * D;            // K*D

    prep_kernel<<<K, 64, 0, stream>>>(embed, e_sq, e_hi, e_lo, cacc);
    fused_kernel<<<N / TM, 256, 0, stream>>>(x, embed, e_hi, e_lo, e_sq,
                                             cacc, q_out, ind_out, K);
    finalize_kernel<<<1, 256, 0, stream>>>(cacc, loss_out, N, K);
}

// Round 3
// 225.506 us; speedup vs baseline: 3.2815x; 1.0006x over previous
//
#include <hip/hip_runtime.h>
#include <math.h>

#define D        128
#define KCODES   2048
#define NPTS     32768
#define AS       136         // halves per LDS point-row (128 + 8 pad)
#define INV_T    (1.0f / 0.9f)
#define LO_SCALE 4096.0f
#define LO_INV   (1.0f / 4096.0f)
#define CHUNK    64          // points staged per chunk
#define NCHUNK   8           // chunks per block -> 512 points per block
#define PSLICES  64
#define CSLICES  8           // 8 x 256 codes

typedef _Float16 half8 __attribute__((ext_vector_type(8)));
typedef _Float16 half4 __attribute__((ext_vector_type(4)));
typedef float    f32x4 __attribute__((ext_vector_type(4)));

// ---------------------------------------------------------------------------
// Prep: e_sq[c], fp16 hi/lo split of embed (lo pre-scaled), zero classacc.
// ---------------------------------------------------------------------------
__global__ void prep_kernel(const float* __restrict__ embed,
                            float* __restrict__ e_sq,
                            _Float16* __restrict__ e_hi,
                            _Float16* __restrict__ e_lo,
                            float* __restrict__ classacc) {
    const int c = blockIdx.x;
    const int t = threadIdx.x;  // 0..63
    float v0 = embed[(size_t)c * D + t];
    float v1 = embed[(size_t)c * D + 64 + t];
    _Float16 h0 = (_Float16)v0;
    _Float16 h1 = (_Float16)v1;
    e_hi[(size_t)c * D + t]      = h0;
    e_hi[(size_t)c * D + 64 + t] = h1;
    e_lo[(size_t)c * D + t]      = (_Float16)((v0 - (float)h0) * LO_SCALE);
    e_lo[(size_t)c * D + 64 + t] = (_Float16)((v1 - (float)h1) * LO_SCALE);
    float s = v0 * v0 + v1 * v1;
    #pragma unroll
    for (int off = 32; off > 0; off >>= 1) s += __shfl_down(s, off, 64);
    if (t == 0) {
        e_sq[c] = s;
        classacc[c] = 0.0f;
    }
}

// stage one 64-point chunk: fp32 x -> hi/lo halves in LDS
__device__ __forceinline__ void stage_x(const float4* __restrict__ x4,
                                        _Float16* ahi, _Float16* alo,
                                        int pbase, int tid) {
    #pragma unroll
    for (int it = 0; it < 8; ++it) {
        int j = tid + it * 256;       // 2048 float4 = 64 rows x 32
        int row = j >> 5;
        int d4 = j & 31;
        float4 v = x4[(size_t)(pbase + row) * 32 + d4];
        half4 h, l4;
        h.x = (_Float16)v.x; h.y = (_Float16)v.y;
        h.z = (_Float16)v.z; h.w = (_Float16)v.w;
        l4.x = (_Float16)((v.x - (float)h.x) * LO_SCALE);
        l4.y = (_Float16)((v.y - (float)h.y) * LO_SCALE);
        l4.z = (_Float16)((v.z - (float)h.z) * LO_SCALE);
        l4.w = (_Float16)((v.w - (float)h.w) * LO_SCALE);
        *(half4*)&ahi[row * AS + d4 * 4] = h;
        *(half4*)&alo[row * AS + d4 * 4] = l4;
    }
}

// ---------------------------------------------------------------------------
// Sweep A (code-resident): each wave holds 64 codes' B-frags in registers.
// Streams 512 points via LDS; per point computes partial (max, argmax, l)
// over this block's 256 codes; block-combines into [CSLICES][NPTS] partials.
// ---------------------------------------------------------------------------
__global__ __launch_bounds__(256, 2)
void sweepA_kernel(const float* __restrict__ x,
                   const _Float16* __restrict__ e_hi_g,
                   const _Float16* __restrict__ e_lo_g,
                   const float* __restrict__ e_sq_g,
                   float* __restrict__ pm, float* __restrict__ pl,
                   int* __restrict__ pidx) {
    __shared__ _Float16 ahi[CHUNK * AS];   // 17.4 KB
    __shared__ _Float16 alo[CHUNK * AS];   // 17.4 KB
    __shared__ float cm[4][CHUNK];
    __shared__ float cl[4][CHUNK];
    __shared__ int   ci[4][CHUNK];

    const int tid  = threadIdx.x;
    const int w    = tid >> 6;
    const int lane = tid & 63;
    const int col  = lane & 15;
    const int quad = lane >> 4;
    const int cslice = blockIdx.y;
    const int pbase0 = blockIdx.x * (CHUNK * NCHUNK);
    const int c0w = cslice * 256 + w * 64;

    // resident B fragments + e_sq for this wave's 64 codes
    half8 bhi[4][4], blo[4][4];
    float esq_r[4];
    #pragma unroll
    for (int ct = 0; ct < 4; ++ct) {
        esq_r[ct] = e_sq_g[c0w + 16 * ct + col];
        #pragma unroll
        for (int kk = 0; kk < 4; ++kk) {
            size_t off = (size_t)(c0w + 16 * ct + col) * D + kk * 32 + quad * 8;
            bhi[ct][kk] = *(const half8*)(e_hi_g + off);
            blo[ct][kk] = *(const half8*)(e_lo_g + off);
        }
    }

    const float4* x4 = (const float4*)x;

    for (int chunk = 0; chunk < NCHUNK; ++chunk) {
        const int pbase = pbase0 + chunk * CHUNK;
        __syncthreads();
        stage_x(x4, ahi, alo, pbase, tid);
        __syncthreads();

        #pragma unroll
        for (int p = 0; p < 4; ++p) {
            half8 Ahi[4], Alo[4];
            #pragma unroll
            for (int kk = 0; kk < 4; ++kk) {
                int off = (16 * p + col) * AS + kk * 32 + quad * 8;
                Ahi[kk] = *(const half8*)&ahi[off];
                Alo[kk] = *(const half8*)&alo[off];
            }
            f32x4 chh[4], cx[4];
            #pragma unroll
            for (int ct = 0; ct < 4; ++ct) { chh[ct] = (f32x4){0,0,0,0}; cx[ct] = (f32x4){0,0,0,0}; }
            #pragma unroll
            for (int kk = 0; kk < 4; ++kk) {
                #pragma unroll
                for (int ct = 0; ct < 4; ++ct) {
                    chh[ct] = __builtin_amdgcn_mfma_f32_16x16x32_f16(Ahi[kk], bhi[ct][kk], chh[ct], 0, 0, 0);
                    cx[ct]  = __builtin_amdgcn_mfma_f32_16x16x32_f16(Ahi[kk], blo[ct][kk], cx[ct], 0, 0, 0);
                    cx[ct]  = __builtin_amdgcn_mfma_f32_16x16x32_f16(Alo[kk], bhi[ct][kk], cx[ct], 0, 0, 0);
                }
            }
            // epilogue: per lane, 4 point-rows x its col across 4 code-tiles
            float lp[4] = {0.f, 0.f, 0.f, 0.f};
            float bv[4] = {-INFINITY, -INFINITY, -INFINITY, -INFINITY};
            int   bi[4] = {0, 0, 0, 0};
            #pragma unroll
            for (int ct = 0; ct < 4; ++ct) {
                int code = c0w + 16 * ct + col;
                #pragma unroll
                for (int r = 0; r < 4; ++r) {
                    float s = 2.0f * (chh[ct][r] + cx[ct][r] * LO_INV) - esq_r[ct];
                    lp[r] += __expf(s * INV_T);
                    if (s > bv[r]) { bv[r] = s; bi[r] = code; }  // ct ascends -> first index
                }
            }
            // reduce across the 16 cols
            #pragma unroll
            for (int r = 0; r < 4; ++r) {
                float v = bv[r]; int idx = bi[r]; float l = lp[r];
                #pragma unroll
                for (int off = 8; off >= 1; off >>= 1) {
                    float ov = __shfl_xor(v, off, 16);
                    int   oi = __shfl_xor(idx, off, 16);
                    float ol = __shfl_xor(l, off, 16);
                    l += ol;
                    if (ov > v || (ov == v && oi < idx)) { v = ov; idx = oi; }
                }
                if (col == 0) {
                    int row = p * 16 + quad * 4 + r;
                    cm[w][row] = v; cl[w][row] = l; ci[w][row] = idx;
                }
            }
        }
        __syncthreads();
        if (tid < CHUNK) {
            float bm = cm[0][tid]; int bidx = ci[0][tid]; float l = cl[0][tid];
            #pragma unroll
            for (int ww = 1; ww < 4; ++ww) {   // waves ascend in code -> strict > keeps first
                float v = cm[ww][tid]; int idx = ci[ww][tid];
                l += cl[ww][tid];
                if (v > bm) { bm = v; bidx = idx; }
            }
            size_t o = (size_t)cslice * NPTS + pbase + tid;
            pm[o] = bm; pl[o] = l; pidx[o] = bidx;
        }
    }
}

// ---------------------------------------------------------------------------
// Combine: per point, reduce 8 code-slice partials -> r=1/sum(l), argmax.
// ---------------------------------------------------------------------------
__global__ void combine_kernel(const float* __restrict__ pm, const float* __restrict__ pl,
                               const int* __restrict__ pidx,
                               float* __restrict__ r_buf, int* __restrict__ idx_buf,
                               float* __restrict__ ind_out) {
    const int p = blockIdx.x * 256 + threadIdx.x;
    float bm = -INFINITY; int bi = 0; float l = 0.0f;
    #pragma unroll
    for (int sl = 0; sl < CSLICES; ++sl) {   // slices ascend in code
        size_t o = (size_t)sl * NPTS + p;
        float v = pm[o];
        l += pl[o];
        if (v > bm) { bm = v; bi = pidx[o]; }
    }
    r_buf[p] = 1.0f / l;
    idx_buf[p] = bi;
    ind_out[p] = (float)bi;
}

// ---------------------------------------------------------------------------
// Sweep B (code-resident): class accumulation into per-lane registers,
// one global atomicAdd per code per wave at the end.
// ---------------------------------------------------------------------------
__global__ __launch_bounds__(256, 2)
void sweepB_kernel(const float* __restrict__ x,
                   const _Float16* __restrict__ e_hi_g,
                   const _Float16* __restrict__ e_lo_g,
                   const float* __restrict__ e_sq_g,
                   const float* __restrict__ r_buf,
                   float* __restrict__ classacc) {
    __shared__ _Float16 ahi[CHUNK * AS];
    __shared__ _Float16 alo[CHUNK * AS];
    __shared__ float r_s[CHUNK];

    const int tid  = threadIdx.x;
    const int w    = tid >> 6;
    const int lane = tid & 63;
    const int col  = lane & 15;
    const int quad = lane >> 4;
    const int cslice = blockIdx.y;
    const int pbase0 = blockIdx.x * (CHUNK * NCHUNK);
    const int c0w = cslice * 256 + w * 64;

    half8 bhi[4][4], blo[4][4];
    float esq_r[4];
    #pragma unroll
    for (int ct = 0; ct < 4; ++ct) {
        esq_r[ct] = e_sq_g[c0w + 16 * ct + col];
        #pragma unroll
        for (int kk = 0; kk < 4; ++kk) {
            size_t off = (size_t)(c0w + 16 * ct + col) * D + kk * 32 + quad * 8;
            bhi[ct][kk] = *(const half8*)(e_hi_g + off);
            blo[ct][kk] = *(const half8*)(e_lo_g + off);
        }
    }

    const float4* x4 = (const float4*)x;
    float csum[4] = {0.f, 0.f, 0.f, 0.f};

    for (int chunk = 0; chunk < NCHUNK; ++chunk) {
        const int pbase = pbase0 + chunk * CHUNK;
        __syncthreads();
        stage_x(x4, ahi, alo, pbase, tid);
        if (tid < CHUNK) r_s[tid] = r_buf[pbase + tid];
        __syncthreads();

        #pragma unroll
        for (int p = 0; p < 4; ++p) {
            half8 Ahi[4], Alo[4];
            #pragma unroll
            for (int kk = 0; kk < 4; ++kk) {
                int off = (16 * p + col) * AS + kk * 32 + quad * 8;
                Ahi[kk] = *(const half8*)&ahi[off];
                Alo[kk] = *(const half8*)&alo[off];
            }
            f32x4 chh[4], cx[4];
            #pragma unroll
            for (int ct = 0; ct < 4; ++ct) { chh[ct] = (f32x4){0,0,0,0}; cx[ct] = (f32x4){0,0,0,0}; }
            #pragma unroll
            for (int kk = 0; kk < 4; ++kk) {
                #pragma unroll
                for (int ct = 0; ct < 4; ++ct) {
                    chh[ct] = __builtin_amdgcn_mfma_f32_16x16x32_f16(Ahi[kk], bhi[ct][kk], chh[ct], 0, 0, 0);
                    cx[ct]  = __builtin_amdgcn_mfma_f32_16x16x32_f16(Ahi[kk], blo[ct][kk], cx[ct], 0, 0, 0);
                    cx[ct]  = __builtin_amdgcn_mfma_f32_16x16x32_f16(Alo[kk], bhi[ct][kk], cx[ct], 0, 0, 0);
                }
            }
            float rr[4];
            #pragma unroll
            for (int r = 0; r < 4; ++r) rr[r] = r_s[p * 16 + quad * 4 + r];
            #pragma unroll
            for (int ct = 0; ct < 4; ++ct) {
                #pragma unroll
                for (int r = 0; r < 4; ++r) {
                    float s = 2.0f * (chh[ct][r] + cx[ct][r] * LO_INV) - esq_r[ct];
                    csum[ct] += __expf(s * INV_T) * rr[r];
                }
            }
        }
    }

    #pragma unroll
    for (int ct = 0; ct < 4; ++ct) {
        float v = csum[ct];
        v += __shfl_xor(v, 16, 64);
        v += __shfl_xor(v, 32, 64);
        if (quad == 0) atomicAdd(&classacc[c0w + 16 * ct + col], v);
    }
}

// ---------------------------------------------------------------------------
// Gather quantize rows.
// ---------------------------------------------------------------------------
__global__ void gather_kernel(const float* __restrict__ embed,
                              const int* __restrict__ idx_buf,
                              float* __restrict__ q_out) {
    const int j = blockIdx.x * 256 + threadIdx.x;   // one float4 each
    const int row = j >> 5;
    const int d4 = j & 31;
    reinterpret_cast<float4*>(q_out)[(size_t)row * 32 + d4] =
        reinterpret_cast<const float4*>(embed)[(size_t)idx_buf[row] * 32 + d4];
}

// ---------------------------------------------------------------------------
__global__ void finalize_kernel(const float* __restrict__ classacc,
                                float* __restrict__ loss_out, int N, int K) {
    __shared__ float red[256];
    const int tid = threadIdx.x;
    float s = 0.0f;
    const float invN = 1.0f / (float)N;
    for (int i = tid; i < K; i += 256) {
        float cp = classacc[i] * invN;
        s += cp * logf(cp + 1e-6f);
    }
    red[tid] = s;
    __syncthreads();
    for (int off = 128; off > 0; off >>= 1) {
        if (tid < off) red[tid] += red[tid + off];
        __syncthreads();
    }
    if (tid == 0) loss_out[0] = red[0];
}

extern "C" void kernel_launch(void* const* d_in, const int* in_sizes, int n_in,
                              void* d_out, int out_size, void* d_ws, size_t ws_size,
                              hipStream_t stream) {
    const float* x     = (const float*)d_in[0];
    const float* embed = (const float*)d_in[1];

    float* out      = (float*)d_out;
    float* q_out    = out;
    float* ind_out  = out + (size_t)NPTS * D;
    float* loss_out = ind_out + NPTS;

    float*    e_sq  = (float*)d_ws;                       // K
    float*    cacc  = e_sq + KCODES;                      // K
    _Float16* e_hi  = (_Float16*)(cacc + KCODES);         // K*D
    _Float16* e_lo  = e_hi + (size_t)KCODES * D;          // K*D
    float*    pm    = (float*)(e_lo + (size_t)KCODES * D);// 8*N
    float*    pl    = pm + (size_t)CSLICES * NPTS;        // 8*N
    int*      pidx  = (int*)(pl + (size_t)CSLICES * NPTS);// 8*N
    float*    r_buf = (float*)(pidx + (size_t)CSLICES * NPTS); // N
    int*      idx_buf = (int*)(r_buf + NPTS);             // N

    dim3 sgrid(PSLICES, CSLICES);

    prep_kernel<<<KCODES, 64, 0, stream>>>(embed, e_sq, e_hi, e_lo, cacc);
    sweepA_kernel<<<sgrid, 256, 0, stream>>>(x, e_hi, e_lo, e_sq, pm, pl, pidx);
    combine_kernel<<<NPTS / 256, 256, 0, stream>>>(pm, pl, pidx, r_buf, idx_buf, ind_out);
    sweepB_kernel<<<sgrid, 256, 0, stream>>>(x, e_hi, e_lo, e_sq, r_buf, cacc);
    gather_kernel<<<NPTS * 32 / 256, 256, 0, stream>>>(embed, idx_buf, q_out);
    finalize_kernel<<<1, 256, 0, stream>>>(cacc, loss_out, NPTS, KCODES);
}